// Round 8
// baseline (54.525 us; speedup 1.0000x reference)
//
#include <hip/hip_runtime.h>

// Permute: out = X @ Q where Q is a one-hot permutation matrix.
// (X@Q)[b][j] = X[b][inv[j]] with inv = perm^{-1}, recovered by scanning Q.
//
// R8 = R7 + wave-private gather: 64-thread blocks (1 wave, 1 row, 16 KB LDS),
// NO __syncthreads. The wave issues its 16 global_load_lds, then its idx
// loads (after -> in-order vmcnt retirement: idx ready implies LDS ready),
// one wave-local s_waitcnt vmcnt(0), gathers from LDS, nt-stores. 10 blocks/CU
// (LDS-capped) keep 160 KB of staging in flight per CU with zero barriers.

#define FEATURES 4096
#define BATCH 8192
#define Q4R (FEATURES / 4)          // 1024 float4 per row
#define WPT (Q4R / 64)              // 16 float4 per thread (64-thread block)

typedef const __attribute__((address_space(1))) void* gptr_t;
typedef __attribute__((address_space(3))) void* lptr_t;
typedef float __attribute__((ext_vector_type(4))) floatx4;   // native vec for nt store

// Kernel 1: scan Q (FEATURES x FEATURES, row-major) for nonzeros.
// Q[i][j] != 0  =>  perm[i] == j  =>  inv[j] = i.
// Exactly one nonzero per column => every inv[j] written exactly once per call.
__global__ __launch_bounds__(256) void build_inv_kernel(
    const float4* __restrict__ Q4, int* __restrict__ inv, int total4) {
    int idx = blockIdx.x * blockDim.x + threadIdx.x;
    int stride = gridDim.x * blockDim.x;
    for (int i = idx; i < total4; i += stride) {
        float4 v = Q4[i];
        if (v.x == 0.f && v.y == 0.f && v.z == 0.f && v.w == 0.f) continue;
        int base = i << 2;                 // flat element index
        int row  = base >> 12;             // / FEATURES (4096)
        int col  = base & (FEATURES - 1);  // % FEATURES
        if (v.x != 0.f) inv[col + 0] = row;
        if (v.y != 0.f) inv[col + 1] = row;
        if (v.z != 0.f) inv[col + 2] = row;
        if (v.w != 0.f) inv[col + 3] = row;
    }
}

// Kernel 2: one wave per block, one row per block, barrier-free.
__global__ __launch_bounds__(64) void permute_wave_kernel(
    const float4* __restrict__ X4, const int4* __restrict__ inv4,
    float* __restrict__ out) {
    __shared__ float row[FEATURES];                // 16 KB -> 10 blocks/CU
    float4* row4 = (float4*)row;
    const int t = threadIdx.x;                     // lane 0..63
    const size_t b = blockIdx.x;

    // 1) Issue all staging loads first (16 x 1 KB per wave, async to LDS).
    const float4* __restrict__ x = X4 + b * Q4R;
#pragma unroll
    for (int i = 0; i < WPT; ++i) {
        __builtin_amdgcn_global_load_lds((gptr_t)(x + t + i * 64),
                                         (lptr_t)(row4 + t + i * 64), 16, 0, 0);
    }

    // 2) idx loads AFTER the staging issues: in-order vmcnt retirement means
    //    "idx in registers" implies "all earlier gll writes landed in LDS".
    int4 idx[WPT];
#pragma unroll
    for (int i = 0; i < WPT; ++i) idx[i] = inv4[t + i * 64];

    // 3) Wave-local drain (no block barrier). sched_barrier pins the ds_reads
    //    below from being hoisted above the wait (guide rule 18).
    asm volatile("s_waitcnt vmcnt(0)" ::: "memory");
    __builtin_amdgcn_sched_barrier(0);

    // 4) Gather from LDS (random ~2-way conflicts, free) -> coalesced nt store.
    floatx4* __restrict__ o = (floatx4*)(out + b * (size_t)FEATURES);
#pragma unroll
    for (int i = 0; i < WPT; ++i) {
        int4 id = idx[i];
        floatx4 v;
        v.x = row[id.x];
        v.y = row[id.y];
        v.z = row[id.z];
        v.w = row[id.w];
        __builtin_nontemporal_store(v, o + t + i * 64);  // 16 B/lane, 1 KB/wave
    }
}

extern "C" void kernel_launch(void* const* d_in, const int* in_sizes, int n_in,
                              void* d_out, int out_size, void* d_ws, size_t ws_size,
                              hipStream_t stream) {
    const float* X = (const float*)d_in[0];
    const float* Q = (const float*)d_in[1];
    float* out = (float*)d_out;
    int* inv = (int*)d_ws;  // 4096 ints = 16 KB scratch

    const int total4 = (FEATURES * FEATURES) / 4;  // 4M float4 quads
    build_inv_kernel<<<2048, 256, 0, stream>>>((const float4*)Q, inv, total4);
    permute_wave_kernel<<<BATCH, 64, 0, stream>>>(
        (const float4*)X, (const int4*)inv, out);
}